// Round 1
// baseline (3736.644 us; speedup 1.0000x reference)
//
#include <hip/hip_runtime.h>
#include <cstddef>

#define EMBED   768
#define NHEADS  12
#define HDIM    64
#define KSZ     7
#define IMG_H   64
#define IMG_W   64
#define BATCH   8
#define NTOK    (BATCH*IMG_H*IMG_W)   /* 32768 */
#define QKV_N   (3*EMBED)             /* 2304  */

// out[m][n] = sum_k A[m][k] * W[n][k] + bias[n]; if (n < scaleN) *= scale
// A: M x K row-major, W: N x K row-major. BM=BN=64, BK=16, 256 threads, 4x4/thread.
template<int BM, int BN, int BK>
__global__ __launch_bounds__(256)
void gemm_bias_kernel(const float* __restrict__ A, const float* __restrict__ W,
                      const float* __restrict__ bias, float* __restrict__ out,
                      int M, int N, int K, int scaleN, float scale)
{
    __shared__ float As[BK][BM];
    __shared__ float Bs[BK][BN];
    const int t  = threadIdx.x;
    const int bm = blockIdx.x * BM;
    const int bn = blockIdx.y * BN;
    const int tm = (t >> 4) * 4;     // 0..60
    const int tn = (t & 15) * 4;     // 0..60
    const int lr = t >> 2;           // 0..63 (row within tile for loads)
    const int lc = (t & 3) * 4;      // 0,4,8,12 (col within K-tile)

    float acc[4][4] = {{0.f}};

    for (int k0 = 0; k0 < K; k0 += BK) {
        float4 a = *(const float4*)(A + (size_t)(bm + lr) * K + k0 + lc);
        float4 b = *(const float4*)(W + (size_t)(bn + lr) * K + k0 + lc);
        __syncthreads();   // protect LDS from previous iteration's readers
        As[lc+0][lr] = a.x; As[lc+1][lr] = a.y; As[lc+2][lr] = a.z; As[lc+3][lr] = a.w;
        Bs[lc+0][lr] = b.x; Bs[lc+1][lr] = b.y; Bs[lc+2][lr] = b.z; Bs[lc+3][lr] = b.w;
        __syncthreads();
        #pragma unroll
        for (int kk = 0; kk < BK; ++kk) {
            float4 av = *(const float4*)&As[kk][tm];
            float4 bv = *(const float4*)&Bs[kk][tn];
            float am[4] = {av.x, av.y, av.z, av.w};
            float bw[4] = {bv.x, bv.y, bv.z, bv.w};
            #pragma unroll
            for (int i = 0; i < 4; ++i)
                #pragma unroll
                for (int j = 0; j < 4; ++j)
                    acc[i][j] = fmaf(am[i], bw[j], acc[i][j]);
        }
    }

    #pragma unroll
    for (int i = 0; i < 4; ++i) {
        const size_t row = (size_t)(bm + tm + i) * N;
        #pragma unroll
        for (int j = 0; j < 4; ++j) {
            const int n = bn + tn + j;
            float v = acc[i][j] + bias[n];
            if (n < scaleN) v *= scale;
            out[row + n] = v;
        }
    }
}

// One wave (64 lanes) per (head, pixel). lane = head-dim index.
// qkv layout: [pixel][2304] with q at +0 (pre-scaled), k at +768, v at +1536,
// each [head*64 + d].
__global__ __launch_bounds__(256)
void natten_kernel(const float* __restrict__ qkv, float* __restrict__ attn_out)
{
    const int wave = threadIdx.x >> 6;
    const int lane = threadIdx.x & 63;
    const int task = blockIdx.x * 4 + wave;       // head * 32768 + pixel
    const int head = task >> 15;
    const int pixel = task & (NTOK - 1);
    const int b = pixel >> 12;
    const int i = (pixel >> 6) & 63;
    const int j = pixel & 63;
    const int si = min(max(i - 3, 0), IMG_H - KSZ);
    const int sj = min(max(j - 3, 0), IMG_W - KSZ);

    const size_t hoff = (size_t)head * HDIM + lane;
    const float qd = qkv[(size_t)pixel * QKV_N + hoff];   // already scaled

    // ---- logits: 49 dot products, each a full 64-lane butterfly reduce ----
    float logit = -INFINITY;
    #pragma unroll
    for (int n = 0; n < KSZ * KSZ; ++n) {
        const int ni = si + n / KSZ;
        const int nj = sj + n % KSZ;
        const int np = (b * IMG_H + ni) * IMG_W + nj;
        const float kd = qkv[(size_t)np * QKV_N + EMBED + hoff];
        float p = qd * kd;
        #pragma unroll
        for (int m = 1; m < 64; m <<= 1) p += __shfl_xor(p, m);
        if (lane == n) logit = p;
    }

    // ---- softmax across lanes 0..48 ----
    float mx = logit;
    #pragma unroll
    for (int m = 1; m < 64; m <<= 1) mx = fmaxf(mx, __shfl_xor(mx, m));
    const float e = (lane < KSZ * KSZ) ? __expf(logit - mx) : 0.f;
    float s = e;
    #pragma unroll
    for (int m = 1; m < 64; m <<= 1) s += __shfl_xor(s, m);
    const float inv = 1.f / s;

    // ---- weighted V accumulation ----
    float acc = 0.f;
    #pragma unroll
    for (int n = 0; n < KSZ * KSZ; ++n) {
        const int ni = si + n / KSZ;
        const int nj = sj + n % KSZ;
        const int np = (b * IMG_H + ni) * IMG_W + nj;
        const float vd = qkv[(size_t)np * QKV_N + 2 * EMBED + hoff];
        const float pn = __shfl(e, n) * inv;
        acc = fmaf(pn, vd, acc);
    }

    attn_out[(size_t)pixel * EMBED + hoff] = acc;
}

extern "C" void kernel_launch(void* const* d_in, const int* in_sizes, int n_in,
                              void* d_out, int out_size, void* d_ws, size_t ws_size,
                              hipStream_t stream)
{
    const float* x      = (const float*)d_in[0];
    const float* w_qkv  = (const float*)d_in[1];
    const float* b_qkv  = (const float*)d_in[2];
    const float* w_proj = (const float*)d_in[3];
    const float* b_proj = (const float*)d_in[4];
    float* out = (float*)d_out;

    float* qkv  = (float*)d_ws;                          // NTOK * 2304 fp32
    float* attn = qkv + (size_t)NTOK * QKV_N;            // NTOK * 768  fp32

    const float scale = 0.125f;  // HDIM^-0.5

    // QKV projection (+bias, q pre-scaled)
    dim3 g1(NTOK / 64, QKV_N / 64);
    gemm_bias_kernel<64, 64, 16><<<g1, 256, 0, stream>>>(
        x, w_qkv, b_qkv, qkv, NTOK, QKV_N, EMBED, EMBED, scale);

    // Neighborhood attention: one wave per (head, pixel)
    natten_kernel<<<(NTOK * NHEADS) / 4, 256, 0, stream>>>(qkv, attn);

    // Output projection
    dim3 g2(NTOK / 64, EMBED / 64);
    gemm_bias_kernel<64, 64, 16><<<g2, 256, 0, stream>>>(
        attn, w_proj, b_proj, out, NTOK, EMBED, EMBED, 0, 1.0f);
}

// Round 3
// 438.440 us; speedup vs baseline: 8.5226x; 8.5226x over previous
//
#include <hip/hip_runtime.h>
#include <cstddef>

#define EMBED   768
#define NHEADS  12
#define HDIM    64
#define KSZ     7
#define IMG_H   64
#define IMG_W   64
#define BATCH   8
#define NTOK    (BATCH*IMG_H*IMG_W)   /* 32768 */
#define QKV_N   (3*EMBED)             /* 2304  */
#define UNION   22
#define NUROWS  (UNION*UNION)         /* 484 */
#define KPAD    72                    /* LDS row stride in ushorts: 144 B -> bank-quad rotates per row */

typedef unsigned short ushort_t;
typedef __attribute__((ext_vector_type(8))) short  bf16x8;
typedef __attribute__((ext_vector_type(4))) float  f32x4;
typedef __attribute__((ext_vector_type(8))) unsigned short u16x8;
typedef __attribute__((ext_vector_type(4))) unsigned short u16x4;

__device__ __forceinline__ float bf2f(unsigned short u) {
    return __uint_as_float(((unsigned int)u) << 16);
}
__device__ __forceinline__ unsigned short f2bf(float f) {
    unsigned int u = __float_as_uint(f);
    u += 0x7FFFu + ((u >> 16) & 1u);      // RNE
    return (unsigned short)(u >> 16);
}

__device__ __forceinline__ void gload_lds16(const void* g, void* l) {
    __builtin_amdgcn_global_load_lds(
        (const __attribute__((address_space(1))) unsigned int*)g,
        (__attribute__((address_space(3))) unsigned int*)l, 16, 0, 0);
}

// ---------------- fp32 -> bf16 conversion ----------------
__global__ __launch_bounds__(256)
void cvt_bf16_kernel(const float* __restrict__ in, unsigned short* __restrict__ out, int n4)
{
    int i = blockIdx.x * 256 + threadIdx.x;
    if (i < n4) {
        float4 f = *(const float4*)(in + (size_t)i * 4);
        u16x4 o;
        o[0] = f2bf(f.x); o[1] = f2bf(f.y); o[2] = f2bf(f.z); o[3] = f2bf(f.w);
        *(u16x4*)(out + (size_t)i * 4) = o;
    }
}

// ---------------- bf16 MFMA GEMM: out[m][n] = A[m][:] . W[n][:] + bias[n] ----------------
// A: M x K bf16 row-major, W: N x K bf16 row-major. 128x128 tile, BK=32, 256 thr (4 waves),
// wave -> 64x64 subtile, 4x4 frags of 16x16x32 MFMA. BF16OUT selects bf16 vs fp32 output.
template<int BF16OUT>
__global__ __launch_bounds__(256)
void mfma_gemm(const unsigned short* __restrict__ A, const unsigned short* __restrict__ W,
               const float* __restrict__ bias, void* __restrict__ outp,
               int N, int K, int scaleN, float scale)
{
    __shared__ unsigned short As[128 * 32];
    __shared__ unsigned short Bs[128 * 32];
    const int t = threadIdx.x;
    const int l = t & 63, w = t >> 6;
    const int bm = blockIdx.x * 128, bn = blockIdx.y * 128;
    const int wr = (w >> 1) * 64, wc = (w & 1) * 64;

    f32x4 acc[4][4] = {};

    const int srow = t >> 2;            // 0..63
    const int scol = (t & 3) * 8;
    unsigned short* ldsA0 = As + w * 512;
    unsigned short* ldsA1 = As + 2048 + w * 512;
    unsigned short* ldsB0 = Bs + w * 512;
    unsigned short* ldsB1 = Bs + 2048 + w * 512;
    const unsigned short* gA0 = A + (size_t)(bm + srow) * K + scol;
    const unsigned short* gA1 = A + (size_t)(bm + 64 + srow) * K + scol;
    const unsigned short* gB0 = W + (size_t)(bn + srow) * K + scol;
    const unsigned short* gB1 = W + (size_t)(bn + 64 + srow) * K + scol;

    const unsigned short* ra = As + (size_t)(wr + (l & 15)) * 32 + (l >> 4) * 8;
    const unsigned short* rb = Bs + (size_t)(wc + (l & 15)) * 32 + (l >> 4) * 8;

    for (int k0 = 0; k0 < K; k0 += 32) {
        __syncthreads();
        gload_lds16(gA0 + k0, ldsA0);
        gload_lds16(gA1 + k0, ldsA1);
        gload_lds16(gB0 + k0, ldsB0);
        gload_lds16(gB1 + k0, ldsB1);
        __syncthreads();
        bf16x8 af[4], bfr[4];
        #pragma unroll
        for (int i = 0; i < 4; ++i) af[i]  = *(const bf16x8*)(ra + i * 16 * 32);
        #pragma unroll
        for (int j = 0; j < 4; ++j) bfr[j] = *(const bf16x8*)(rb + j * 16 * 32);
        #pragma unroll
        for (int i = 0; i < 4; ++i)
            #pragma unroll
            for (int j = 0; j < 4; ++j)
                acc[i][j] = __builtin_amdgcn_mfma_f32_16x16x32_bf16(af[i], bfr[j], acc[i][j], 0, 0, 0);
    }

    const int cr = (l >> 4) * 4;
    const int cc = l & 15;
    #pragma unroll
    for (int i = 0; i < 4; ++i) {
        #pragma unroll
        for (int j = 0; j < 4; ++j) {
            const int col = bn + wc + j * 16 + cc;
            const float bv = bias[col];
            const bool sc = col < scaleN;
            #pragma unroll
            for (int r = 0; r < 4; ++r) {
                const int row = bm + wr + i * 16 + cr + r;
                float v = acc[i][j][r] + bv;
                if (sc) v *= scale;
                if (BF16OUT) ((unsigned short*)outp)[(size_t)row * N + col] = f2bf(v);
                else         ((float*)outp)[(size_t)row * N + col] = v;
            }
        }
    }
}

// ---------------- neighborhood attention ----------------
// Block = (batch, head, 16x16 pixel tile). Stage 22x22 K (then V) union in LDS (bf16,
// KPAD=72 row stride). Thread = one (pixel, head): per-thread dots, ONLINE softmax
// (running max+sum), logits spilled to lws (L2-hot round-trip), then P.V pass.
__device__ __forceinline__ void stage_kv(unsigned short* __restrict__ kv,
                                         const unsigned short* __restrict__ gbase,
                                         size_t pixbase, int t)
{
    const int rt = t >> 2;
    const int d0 = (t & 3) * 16;
    #pragma unroll 1
    for (int r0 = 0; r0 < NUROWS; r0 += 64) {
        const int row = r0 + rt;
        if (row < NUROWS) {
            const int ur = row / UNION;
            const int uc = row - ur * UNION;
            const unsigned short* g = gbase + (pixbase + (size_t)(ur * IMG_W + uc)) * QKV_N + d0;
            u16x8 v0 = *(const u16x8*)g;
            u16x8 v1 = *(const u16x8*)(g + 8);
            unsigned short* dst = kv + row * KPAD + d0;
            *(u16x8*)dst       = v0;
            *(u16x8*)(dst + 8) = v1;
        }
    }
}

__global__ __launch_bounds__(256)
void natten_kernel(const unsigned short* __restrict__ qkv, float* __restrict__ lws,
                   unsigned short* __restrict__ attn_bf)
{
    __shared__ unsigned short kv[NUROWS * KPAD];   // 69,696 B
    const int t = threadIdx.x;
    const int blk = blockIdx.x;                    // b*(12*16) + h*16 + tile
    const int tile = blk & 15;
    const int h = (blk >> 4) % NHEADS;
    const int b = blk / (16 * NHEADS);
    const int ti = (tile >> 2) * 16, tj = (tile & 3) * 16;
    const int ui0 = min(max(ti - 3, 0), IMG_H - UNION);
    const int uj0 = min(max(tj - 3, 0), IMG_W - UNION);
    const int pi = ti + (t >> 4), pj = tj + (t & 15);
    const int si = min(max(pi - 3, 0), IMG_H - KSZ) - ui0;
    const int sj = min(max(pj - 3, 0), IMG_W - KSZ) - uj0;
    const int pix = (b * IMG_H + pi) * IMG_W + pj;
    const size_t pixbase = ((size_t)b * IMG_H + ui0) * IMG_W + uj0;

    // q (bf16, pre-scaled by GEMM1 epilogue) -> f32 regs
    float q[64];
    const unsigned short* qg = qkv + (size_t)pix * QKV_N + h * HDIM;
    #pragma unroll
    for (int d8 = 0; d8 < 8; ++d8) {
        u16x8 f = *(const u16x8*)(qg + d8 * 8);
        #pragma unroll
        for (int e = 0; e < 8; ++e) q[d8 * 8 + e] = bf2f(f[e]);
    }

    stage_kv(kv, qkv + EMBED + h * HDIM, pixbase, t);     // K
    __syncthreads();

    float* myl = lws + ((size_t)h * 49) * NTOK + pix;

    float mx = -1e30f, s = 0.f;
    #pragma unroll 1
    for (int n = 0; n < 49; ++n) {
        const int row = (si + n / 7) * UNION + (sj + n % 7);
        const unsigned short* kr = kv + row * KPAD;
        float acc = 0.f;
        #pragma unroll
        for (int d8 = 0; d8 < 8; ++d8) {
            u16x8 kvv = *(const u16x8*)(kr + d8 * 8);
            #pragma unroll
            for (int e = 0; e < 8; ++e)
                acc = fmaf(q[d8 * 8 + e], bf2f(kvv[e]), acc);
        }
        myl[(size_t)n * NTOK] = acc;
        const float nm = fmaxf(mx, acc);
        s = s * __expf(mx - nm) + __expf(acc - nm);
        mx = nm;
    }

    __syncthreads();                                      // all K reads done
    stage_kv(kv, qkv + 2 * EMBED + h * HDIM, pixbase, t); // V over K
    __syncthreads();

    const float inv = 1.f / s;

    float acc[64];
    #pragma unroll
    for (int d = 0; d < 64; ++d) acc[d] = 0.f;
    #pragma unroll 1
    for (int n = 0; n < 49; ++n) {
        const float pn = __expf(myl[(size_t)n * NTOK] - mx);
        const int row = (si + n / 7) * UNION + (sj + n % 7);
        const unsigned short* vr = kv + row * KPAD;
        #pragma unroll
        for (int d8 = 0; d8 < 8; ++d8) {
            u16x8 vv = *(const u16x8*)(vr + d8 * 8);
            #pragma unroll
            for (int e = 0; e < 8; ++e)
                acc[d8 * 8 + e] = fmaf(pn, bf2f(vv[e]), acc[d8 * 8 + e]);
        }
    }

    unsigned short* og = attn_bf + (size_t)pix * EMBED + h * HDIM;
    #pragma unroll
    for (int d8 = 0; d8 < 8; ++d8) {
        u16x8 o;
        #pragma unroll
        for (int e = 0; e < 8; ++e) o[e] = f2bf(acc[d8 * 8 + e] * inv);
        *(u16x8*)(og + d8 * 8) = o;
    }
}

// ---------------- launch ----------------
extern "C" void kernel_launch(void* const* d_in, const int* in_sizes, int n_in,
                              void* d_out, int out_size, void* d_ws, size_t ws_size,
                              hipStream_t stream)
{
    const float* x      = (const float*)d_in[0];
    const float* w_qkv  = (const float*)d_in[1];
    const float* b_qkv  = (const float*)d_in[2];
    const float* w_proj = (const float*)d_in[3];
    const float* b_proj = (const float*)d_in[4];
    float* out = (float*)d_out;

    // workspace layout (~283 MB total; round-1 proved >= ~403 MB is available)
    char* p = (char*)d_ws;
    unsigned short* qkv = (unsigned short*)p;     p += (size_t)NTOK * QKV_N * 2;       // 151 MB
    float* lws = (float*)p;                       p += (size_t)NHEADS * 49 * NTOK * 4; // 77 MB
    unsigned short* xbf = (unsigned short*)p;     // aliased: x_bf (GEMM1 input) then attn_bf
    unsigned short* attn_bf = xbf;                p += (size_t)NTOK * EMBED * 2;       // 50 MB
    unsigned short* wq_bf = (unsigned short*)p;   p += (size_t)QKV_N * EMBED * 2;      // 3.5 MB
    unsigned short* wp_bf = (unsigned short*)p;   /* 1.2 MB */

    const float scale = 0.125f;  // HDIM^-0.5

    // convert inputs to bf16
    {
        int n4 = NTOK * EMBED / 4;
        cvt_bf16_kernel<<<(n4 + 255) / 256, 256, 0, stream>>>(x, xbf, n4);
        n4 = QKV_N * EMBED / 4;
        cvt_bf16_kernel<<<(n4 + 255) / 256, 256, 0, stream>>>(w_qkv, wq_bf, n4);
        n4 = EMBED * EMBED / 4;
        cvt_bf16_kernel<<<(n4 + 255) / 256, 256, 0, stream>>>(w_proj, wp_bf, n4);
    }

    // QKV projection (bias fused, q columns pre-scaled), bf16 out
    {
        dim3 g(NTOK / 128, QKV_N / 128);
        mfma_gemm<1><<<g, 256, 0, stream>>>(xbf, wq_bf, b_qkv, qkv, QKV_N, EMBED, EMBED, scale);
    }

    // neighborhood attention (writes attn_bf over the xbf region — xbf is dead now)
    natten_kernel<<<BATCH * NHEADS * 16, 256, 0, stream>>>(qkv, lws, attn_bf);

    // output projection, fp32 out
    {
        dim3 g(NTOK / 128, EMBED / 128);
        mfma_gemm<0><<<g, 256, 0, stream>>>(attn_bf, wp_bf, b_proj, out, EMBED, EMBED, 0, 1.0f);
    }
}

// Round 4
// 359.063 us; speedup vs baseline: 10.4067x; 1.2211x over previous
//
#include <hip/hip_runtime.h>
#include <cstddef>

#define EMBED   768
#define NHEADS  12
#define HDIM    64
#define KSZ     7
#define IMG_H   64
#define IMG_W   64
#define BATCH   8
#define NTOK    (BATCH*IMG_H*IMG_W)   /* 32768 */
#define QKV_N   (3*EMBED)             /* 2304  */

typedef __attribute__((ext_vector_type(8))) short  bf16x8;
typedef __attribute__((ext_vector_type(4))) float  f32x4;
typedef __attribute__((ext_vector_type(8))) unsigned short u16x8;
typedef __attribute__((ext_vector_type(4))) unsigned short u16x4;

__device__ __forceinline__ unsigned short f2bf(float f) {
    unsigned int u = __float_as_uint(f);
    u += 0x7FFFu + ((u >> 16) & 1u);      // RNE
    return (unsigned short)(u >> 16);
}

__device__ __forceinline__ void gload_lds16(const void* g, void* l) {
    __builtin_amdgcn_global_load_lds(
        (const __attribute__((address_space(1))) unsigned int*)g,
        (__attribute__((address_space(3))) unsigned int*)l, 16, 0, 0);
}

// ---------------- fp32 -> bf16 conversion ----------------
__global__ __launch_bounds__(256)
void cvt_bf16_kernel(const float* __restrict__ in, unsigned short* __restrict__ out, int n4)
{
    int i = blockIdx.x * 256 + threadIdx.x;
    if (i < n4) {
        float4 f = *(const float4*)(in + (size_t)i * 4);
        u16x4 o;
        o[0] = f2bf(f.x); o[1] = f2bf(f.y); o[2] = f2bf(f.z); o[3] = f2bf(f.w);
        *(u16x4*)(out + (size_t)i * 4) = o;
    }
}

// ---------------- bf16 MFMA GEMM (m97-style, verified round 3) ----------------
template<int BF16OUT>
__global__ __launch_bounds__(256)
void mfma_gemm(const unsigned short* __restrict__ A, const unsigned short* __restrict__ W,
               const float* __restrict__ bias, void* __restrict__ outp,
               int N, int K, int scaleN, float scale)
{
    __shared__ unsigned short As[128 * 32];
    __shared__ unsigned short Bs[128 * 32];
    const int t = threadIdx.x;
    const int l = t & 63, w = t >> 6;
    const int bm = blockIdx.x * 128, bn = blockIdx.y * 128;
    const int wr = (w >> 1) * 64, wc = (w & 1) * 64;

    f32x4 acc[4][4] = {};

    const int srow = t >> 2;
    const int scol = (t & 3) * 8;
    unsigned short* ldsA0 = As + w * 512;
    unsigned short* ldsA1 = As + 2048 + w * 512;
    unsigned short* ldsB0 = Bs + w * 512;
    unsigned short* ldsB1 = Bs + 2048 + w * 512;
    const unsigned short* gA0 = A + (size_t)(bm + srow) * K + scol;
    const unsigned short* gA1 = A + (size_t)(bm + 64 + srow) * K + scol;
    const unsigned short* gB0 = W + (size_t)(bn + srow) * K + scol;
    const unsigned short* gB1 = W + (size_t)(bn + 64 + srow) * K + scol;

    const unsigned short* ra = As + (size_t)(wr + (l & 15)) * 32 + (l >> 4) * 8;
    const unsigned short* rb = Bs + (size_t)(wc + (l & 15)) * 32 + (l >> 4) * 8;

    for (int k0 = 0; k0 < K; k0 += 32) {
        __syncthreads();
        gload_lds16(gA0 + k0, ldsA0);
        gload_lds16(gA1 + k0, ldsA1);
        gload_lds16(gB0 + k0, ldsB0);
        gload_lds16(gB1 + k0, ldsB1);
        __syncthreads();
        bf16x8 af[4], bfr[4];
        #pragma unroll
        for (int i = 0; i < 4; ++i) af[i]  = *(const bf16x8*)(ra + i * 16 * 32);
        #pragma unroll
        for (int j = 0; j < 4; ++j) bfr[j] = *(const bf16x8*)(rb + j * 16 * 32);
        #pragma unroll
        for (int i = 0; i < 4; ++i)
            #pragma unroll
            for (int j = 0; j < 4; ++j)
                acc[i][j] = __builtin_amdgcn_mfma_f32_16x16x32_bf16(af[i], bfr[j], acc[i][j], 0, 0, 0);
    }

    const int cr = (l >> 4) * 4;
    const int cc = l & 15;
    #pragma unroll
    for (int i = 0; i < 4; ++i) {
        #pragma unroll
        for (int j = 0; j < 4; ++j) {
            const int col = bn + wc + j * 16 + cc;
            const float bv = bias[col];
            const bool sc = col < scaleN;
            #pragma unroll
            for (int r = 0; r < 4; ++r) {
                const int row = bm + wr + i * 16 + cr + r;
                float v = acc[i][j][r] + bv;
                if (sc) v *= scale;
                if (BF16OUT) ((unsigned short*)outp)[(size_t)row * N + col] = f2bf(v);
                else         ((float*)outp)[(size_t)row * N + col] = v;
            }
        }
    }
}

// ---------------- MFMA neighborhood attention ----------------
// Block = (b, h, 16x16 tile); wave w = 4-pixel-row band (4 q-tiles of 16 pixels).
// Per-wave window: 10 rows x 22 cols = 220 keys -> 7 chunks of 32. Waves fully
// independent (per-wave LDS, no barriers). S^T = mfma(K,Q) so softmax is lane-local
// (no max-subtract; log2e folded into q-scale). PV uses a per-chunk slot permutation
// sigma(k)=8g+4t+j on the V^T LDS layout that matches the S^T register layout, so P
// needs NO cross-lane movement. Normalize at the end (sum via 2 shfl_xor).
__global__ __launch_bounds__(256)
void natten_kernel(const unsigned short* __restrict__ qkv, unsigned short* __restrict__ attn_bf)
{
    __shared__ unsigned short smem[4 * 5888];   // per wave: K 32x72 + V^T 64x56 (47,104 B total)
    const int t = threadIdx.x;
    const int w = t >> 6, l = t & 63;
    const int c15 = l & 15, g = l >> 4;
    const int blk = blockIdx.x;
    const int tg = blk & 15;
    const int h = (blk >> 4) % NHEADS;
    const int b = blk / (16 * NHEADS);
    const int ti = (tg >> 2) * 16, tj = (tg & 3) * 16;
    const int pi0 = ti + w * 4;
    const int ws = min(max(pi0 - 3, 0), IMG_H - 10);
    const int cs = min(max(tj - 3, 0), IMG_W - 22);
    const int pixbase = b * 4096;

    unsigned short* Kl = smem + w * 5888;
    unsigned short* Vt = Kl + 2304;

    // per-lane masks: cm over window cols for q-col pj; rm[qt] over window rows
    const int pj = tj + c15;
    const int sj = min(max(pj - 3, 0), IMG_W - KSZ);
    const unsigned int cm = 0x7Fu << (sj - cs);
    unsigned int rm[4];
    #pragma unroll
    for (int qt = 0; qt < 4; ++qt) {
        int si = min(max(pi0 + qt - 3, 0), IMG_H - KSZ);
        rm[qt] = 0x7Fu << (si - ws);
    }

    // Q fragments (B-operand): lane holds Q[q=c15][d=dh*32+g*8 ..+7]
    bf16x8 qf[4][2];
    #pragma unroll
    for (int qt = 0; qt < 4; ++qt)
        #pragma unroll
        for (int dh = 0; dh < 2; ++dh)
            qf[qt][dh] = *(const bf16x8*)(qkv +
                (size_t)(pixbase + (pi0 + qt) * 64 + tj + c15) * QKV_N + h * HDIM + dh * 32 + g * 8);

    // staging lane assignment: lane covers chunk-row sr, d-half h5
    const int sr = l & 31;
    const int h5 = l >> 5;
    const int sig = ((sr & 12) << 1) | ((sr & 16) >> 2) | (sr & 3);  // slot perm 8g+4t+j

    u16x8 kst[4], vst[4];

    // stage-load + stage-write chunk 0
    {
        int ur = sr / 22, uc = sr - ur * 22;
        int prow = min(ws + ur, IMG_H - 1);
        const u16x8* gk = (const u16x8*)(qkv +
            (size_t)(pixbase + prow * 64 + cs + uc) * QKV_N + EMBED + h * HDIM + h5 * 32);
        #pragma unroll
        for (int i = 0; i < 4; ++i) { kst[i] = gk[i]; vst[i] = gk[i + 96]; }
    }
    #pragma unroll
    for (int i = 0; i < 4; ++i) *(u16x8*)(Kl + sr * 72 + h5 * 32 + i * 8) = kst[i];
    #pragma unroll
    for (int i = 0; i < 4; ++i)
        #pragma unroll
        for (int e = 0; e < 8; ++e)
            Vt[(h5 * 32 + i * 8 + e) * 56 + sig] = vst[i][e];

    f32x4 oacc[4][4] = {};
    float spart[4] = {0.f, 0.f, 0.f, 0.f};

    #pragma unroll 1
    for (int C = 0; C < 7; ++C) {
        // issue next chunk's global loads early (latency hides under compute)
        if (C < 6) {
            int kk = (C + 1) * 32 + sr;
            int ur = kk / 22, uc = kk - ur * 22;
            int prow = min(ws + ur, IMG_H - 1);
            const u16x8* gk = (const u16x8*)(qkv +
                (size_t)(pixbase + prow * 64 + cs + uc) * QKV_N + EMBED + h * HDIM + h5 * 32);
            #pragma unroll
            for (int i = 0; i < 4; ++i) { kst[i] = gk[i]; vst[i] = gk[i + 96]; }
        }

        // ---- compute chunk C from LDS ----
        bf16x8 ka[2][2], vb[4];
        #pragma unroll
        for (int kt = 0; kt < 2; ++kt)
            #pragma unroll
            for (int dh = 0; dh < 2; ++dh)
                ka[kt][dh] = *(const bf16x8*)(Kl + (kt * 16 + c15) * 72 + dh * 32 + g * 8);
        #pragma unroll
        for (int dt = 0; dt < 4; ++dt)
            vb[dt] = *(const bf16x8*)(Vt + (dt * 16 + c15) * 56 + g * 8);

        // window coords for this lane's S rows (shared across q-tiles)
        int kk0 = C * 32 + 4 * g;
        int a22 = kk0 / 22;
        int uc0 = kk0 - a22 * 22;
        int urx[2][4]; unsigned int cb[2][4];
        #pragma unroll
        for (int kt = 0; kt < 2; ++kt)
            #pragma unroll
            for (int r = 0; r < 4; ++r) {
                int x = uc0 + kt * 16 + r;
                int wrp = x >= 22;
                int uc = x - (wrp ? 22 : 0);
                urx[kt][r] = a22 + wrp;
                cb[kt][r] = (cm >> uc) & 1u;
            }

        #pragma unroll
        for (int qt = 0; qt < 4; ++qt) {
            f32x4 s0 = {}, s1 = {};
            s0 = __builtin_amdgcn_mfma_f32_16x16x32_bf16(ka[0][0], qf[qt][0], s0, 0, 0, 0);
            s0 = __builtin_amdgcn_mfma_f32_16x16x32_bf16(ka[0][1], qf[qt][1], s0, 0, 0, 0);
            s1 = __builtin_amdgcn_mfma_f32_16x16x32_bf16(ka[1][0], qf[qt][0], s1, 0, 0, 0);
            s1 = __builtin_amdgcn_mfma_f32_16x16x32_bf16(ka[1][1], qf[qt][1], s1, 0, 0, 0);
            float p[2][4];
            #pragma unroll
            for (int r = 0; r < 4; ++r) {
                float e0 = exp2f(s0[r]);
                float e1 = exp2f(s1[r]);
                p[0][r] = ((rm[qt] >> urx[0][r]) & cb[0][r]) ? e0 : 0.f;
                p[1][r] = ((rm[qt] >> urx[1][r]) & cb[1][r]) ? e1 : 0.f;
                spart[qt] += p[0][r] + p[1][r];
            }
            unsigned int pk[4];
            asm("v_cvt_pk_bf16_f32 %0, %1, %2" : "=v"(pk[0]) : "v"(p[0][0]), "v"(p[0][1]));
            asm("v_cvt_pk_bf16_f32 %0, %1, %2" : "=v"(pk[1]) : "v"(p[0][2]), "v"(p[0][3]));
            asm("v_cvt_pk_bf16_f32 %0, %1, %2" : "=v"(pk[2]) : "v"(p[1][0]), "v"(p[1][1]));
            asm("v_cvt_pk_bf16_f32 %0, %1, %2" : "=v"(pk[3]) : "v"(p[1][2]), "v"(p[1][3]));
            bf16x8 pa = *(bf16x8*)pk;
            #pragma unroll
            for (int dt = 0; dt < 4; ++dt)
                oacc[qt][dt] = __builtin_amdgcn_mfma_f32_16x16x32_bf16(pa, vb[dt], oacc[qt][dt], 0, 0, 0);
        }

        // stage-write next chunk (after this chunk's LDS reads)
        if (C < 6) {
            #pragma unroll
            for (int i = 0; i < 4; ++i) *(u16x8*)(Kl + sr * 72 + h5 * 32 + i * 8) = kst[i];
            #pragma unroll
            for (int i = 0; i < 4; ++i)
                #pragma unroll
                for (int e = 0; e < 8; ++e)
                    Vt[(h5 * 32 + i * 8 + e) * 56 + sig] = vst[i][e];
        }
    }

    // ---- finalize: row sums across the 4 lane-groups, normalize, store bf16 ----
    #pragma unroll
    for (int qt = 0; qt < 4; ++qt) {
        float s = spart[qt];
        s += __shfl_xor(s, 16);
        s += __shfl_xor(s, 32);
        #pragma unroll
        for (int r = 0; r < 4; ++r) {
            float sb = __shfl(s, 4 * g + r);          // s for output row q'=4g+r
            float inv = __builtin_amdgcn_rcpf(sb);
            size_t obase = (size_t)(pixbase + (pi0 + qt) * 64 + tj + 4 * g + r) * EMBED
                         + h * HDIM + c15;
            #pragma unroll
            for (int dt = 0; dt < 4; ++dt)
                attn_bf[obase + dt * 16] = f2bf(oacc[qt][dt][r] * inv);
        }
    }
}

// ---------------- launch ----------------
extern "C" void kernel_launch(void* const* d_in, const int* in_sizes, int n_in,
                              void* d_out, int out_size, void* d_ws, size_t ws_size,
                              hipStream_t stream)
{
    const float* x      = (const float*)d_in[0];
    const float* w_qkv  = (const float*)d_in[1];
    const float* b_qkv  = (const float*)d_in[2];
    const float* w_proj = (const float*)d_in[3];
    const float* b_proj = (const float*)d_in[4];
    float* out = (float*)d_out;

    // workspace (~206 MB)
    char* p = (char*)d_ws;
    unsigned short* qkv = (unsigned short*)p;     p += (size_t)NTOK * QKV_N * 2;       // 151 MB
    unsigned short* xbf = (unsigned short*)p;     // aliased: x_bf then attn_bf
    unsigned short* attn_bf = xbf;                p += (size_t)NTOK * EMBED * 2;       // 50 MB
    unsigned short* wq_bf = (unsigned short*)p;   p += (size_t)QKV_N * EMBED * 2;      // 3.5 MB
    unsigned short* wp_bf = (unsigned short*)p;

    const float scale = 0.125f * 1.44269504088896f;  // HDIM^-0.5 * log2(e), so exp2(S)=exp(S/log2e)

    {
        int n4 = NTOK * EMBED / 4;
        cvt_bf16_kernel<<<(n4 + 255) / 256, 256, 0, stream>>>(x, xbf, n4);
        n4 = QKV_N * EMBED / 4;
        cvt_bf16_kernel<<<(n4 + 255) / 256, 256, 0, stream>>>(w_qkv, wq_bf, n4);
        n4 = EMBED * EMBED / 4;
        cvt_bf16_kernel<<<(n4 + 255) / 256, 256, 0, stream>>>(w_proj, wp_bf, n4);
    }

    {
        dim3 g1(NTOK / 128, QKV_N / 128);
        mfma_gemm<1><<<g1, 256, 0, stream>>>(xbf, wq_bf, b_qkv, qkv, QKV_N, EMBED, EMBED, scale);
    }

    natten_kernel<<<BATCH * NHEADS * 16, 256, 0, stream>>>(qkv, attn_bf);

    {
        dim3 g2(NTOK / 128, EMBED / 128);
        mfma_gemm<0><<<g2, 256, 0, stream>>>(attn_bf, wp_bf, b_proj, out, EMBED, EMBED, 0, 1.0f);
    }
}